// Round 1
// baseline (280.990 us; speedup 1.0000x reference)
//
#include <hip/hip_runtime.h>
#include <hip/hip_bf16.h>

// out[b,c,l,m] = sum_{s,t} xp[b,c,l+s] * F[c,s,t] * xp[b,c,m+t]
// xp = x zero-padded by 8 on both ends of the last dim.
// x: [8,2,2048] f32, filt: [1,2,17,17] f32, out: [8,2,2048,2048] f32 (256 MB)
// HBM-write-bound: floor ~ 256MB / ~5.5 TB/s ~ 50 us.

#define LN   2048
#define S    17
#define PADW 8
#define TL   64
#define TM   64

__global__ __launch_bounds__(256) void filter_qf_kernel(
    const float* __restrict__ x,
    const float* __restrict__ filt,
    float* __restrict__ out)
{
    // grid: (LN/TM, LN/TL, 16); z = bc = b*2 + c
    const int bc = blockIdx.z;
    const int c  = bc & 1;
    const int l0 = blockIdx.y * TL;
    const int m0 = blockIdx.x * TM;
    const int tid = threadIdx.x;

    __shared__ float sF[S][S];            // F[c][s][t]
    __shared__ float sxl[TL + S - 1];     // xp[l0 .. l0+TL+16)
    __shared__ float sxm[TM + S - 1];     // xp[m0 .. m0+TM+16)
    __shared__ float sxf[TL][S + 1];      // xf[l][t], stride 18 breaks bank aliasing

    const float* __restrict__ xrow = x + (size_t)bc * LN;

    // stage filter slice for this channel
    for (int i = tid; i < S * S; i += 256)
        sF[i / S][i % S] = filt[c * S * S + i];

    // stage the two padded windows (zero outside [0, LN))
    for (int i = tid; i < TL + S - 1; i += 256) {
        int j = l0 + i - PADW;
        sxl[i] = (j >= 0 && j < LN) ? xrow[j] : 0.0f;
    }
    for (int i = tid; i < TM + S - 1; i += 256) {
        int j = m0 + i - PADW;
        sxm[i] = (j >= 0 && j < LN) ? xrow[j] : 0.0f;
    }
    __syncthreads();

    // xf[l][t] = sum_s sxl[l+s] * F[s][t]   (64*17 = 1088 entries / 256 threads)
    for (int i = tid; i < TL * S; i += 256) {
        int l = i / S, t = i % S;
        float acc = 0.0f;
#pragma unroll
        for (int s = 0; s < S; s++)
            acc += sxl[l + s] * sF[s][t];
        sxf[l][t] = acc;
    }
    __syncthreads();

    // 16x16 thread grid, each thread owns a 4l x 4m register tile
    const int tm = (tid & 15) << 2;   // 0..60
    const int tl = (tid >> 4) << 2;   // 0..60

    // m-window in registers: sxm[tm .. tm+20) ; 16B-aligned -> ds_read_b128s
    float w[4 + S - 1];
#pragma unroll
    for (int i = 0; i < 4 + S - 1; i++)
        w[i] = sxm[tm + i];

    float acc[4][4] = {{0.f}};
#pragma unroll
    for (int t = 0; t < S; t++) {
        const float f0 = sxf[tl + 0][t];
        const float f1 = sxf[tl + 1][t];
        const float f2 = sxf[tl + 2][t];
        const float f3 = sxf[tl + 3][t];
#pragma unroll
        for (int j = 0; j < 4; j++) {
            const float b = w[t + j];
            acc[0][j] += f0 * b;
            acc[1][j] += f1 * b;
            acc[2][j] += f2 * b;
            acc[3][j] += f3 * b;
        }
    }

    // coalesced float4 stores
    size_t base = (((size_t)bc * LN) + (size_t)(l0 + tl)) * LN + (size_t)(m0 + tm);
#pragma unroll
    for (int li = 0; li < 4; li++) {
        float4 v = make_float4(acc[li][0], acc[li][1], acc[li][2], acc[li][3]);
        *reinterpret_cast<float4*>(out + base + (size_t)li * LN) = v;
    }
}

extern "C" void kernel_launch(void* const* d_in, const int* in_sizes, int n_in,
                              void* d_out, int out_size, void* d_ws, size_t ws_size,
                              hipStream_t stream) {
    const float* x    = (const float*)d_in[0];   // [8,2,2048]
    const float* filt = (const float*)d_in[1];   // [1,2,17,17]
    float* out = (float*)d_out;                  // [8,2,2048,2048]

    dim3 grid(LN / TM, LN / TL, 16);
    dim3 block(256);
    filter_qf_kernel<<<grid, block, 0, stream>>>(x, filt, out);
}

// Round 3
// 268.476 us; speedup vs baseline: 1.0466x; 1.0466x over previous
//
#include <hip/hip_runtime.h>
#include <hip/hip_bf16.h>

// out[b,c,l,m] = sum_{s,t} xp[b,c,l+s] * F[c,s,t] * xp[b,c,m+t]
// Decomposition: xf[bc,t,l] = sum_s xp[l+s] * F[c,s,t]  (materialized in d_ws, 2.2 MB, t-major)
//                out[bc,l,m] = sum_t xf[bc,t,l] * xp[m+t]
// x: [8,2,2048] f32, filt: [1,2,17,17] f32, out: [8,2,2048,2048] f32 (268 MB)
// HBM-write-bound: floor ~ 268MB / ~6 TB/s ~ 48 us.

#define LN   2048
#define S    17
#define PADW 8
#define TL   64
#define TM   64
#define NBC  16

typedef float f32x4 __attribute__((ext_vector_type(4)));  // clang vector: valid for nontemporal builtins

// ---------------- kernel 1: xf[bc][t][l] = sum_s xp[bc][l+s] * F[c][s][t] -------------
__global__ __launch_bounds__(256) void xf_kernel(
    const float* __restrict__ x,
    const float* __restrict__ filt,
    float* __restrict__ xf)   // [NBC][S][LN]
{
    const int bc = blockIdx.y;
    const int c  = bc & 1;
    const int l  = blockIdx.x * 256 + threadIdx.x;

    __shared__ float sF[S][S];
    for (int i = threadIdx.x; i < S * S; i += 256)
        sF[i / S][i % S] = filt[c * S * S + i];
    __syncthreads();

    const float* __restrict__ xrow = x + (size_t)bc * LN;

    // window xp[l .. l+16] (xp pad 8 each side)
    float w[S];
#pragma unroll
    for (int s = 0; s < S; s++) {
        int j = l + s - PADW;
        w[s] = (j >= 0 && j < LN) ? xrow[j] : 0.0f;
    }

    float acc[S];
#pragma unroll
    for (int t = 0; t < S; t++) acc[t] = 0.0f;
#pragma unroll
    for (int s = 0; s < S; s++) {
        const float ws = w[s];
#pragma unroll
        for (int t = 0; t < S; t++)
            acc[t] += ws * sF[s][t];
    }

    float* __restrict__ xfrow = xf + (size_t)bc * S * LN + l;
#pragma unroll
    for (int t = 0; t < S; t++)
        xfrow[(size_t)t * LN] = acc[t];
}

// ---------------- kernel 2: out tile, store-bound ----------------
__global__ __launch_bounds__(256) void filter_qf_kernel(
    const float* __restrict__ x,
    const float* __restrict__ xf,   // [NBC][S][LN]
    float* __restrict__ out)
{
    const int bc = blockIdx.z;
    const int l0 = blockIdx.y * TL;
    const int m0 = blockIdx.x * TM;
    const int tid = threadIdx.x;

    __shared__ float sxf[S][TL];        // t-major: row = 256 B, b128-friendly
    __shared__ float sxm[TM + S - 1];

    // stage xf tile: 17*64 = 1088 floats, coalesced (L2-resident source)
    const float* __restrict__ xfbase = xf + (size_t)bc * S * LN + l0;
    for (int i = tid; i < S * TL; i += 256) {
        int t = i >> 6, l = i & 63;
        sxf[t][l] = xfbase[(size_t)t * LN + l];
    }
    // stage m-window
    const float* __restrict__ xrow = x + (size_t)bc * LN;
    for (int i = tid; i < TM + S - 1; i += 256) {
        int j = m0 + i - PADW;
        sxm[i] = (j >= 0 && j < LN) ? xrow[j] : 0.0f;
    }
    __syncthreads();

    // 16x16 thread grid, 4l x 4m register tile each
    const int tm = (tid & 15) << 2;
    const int tl = (tid >> 4) << 2;

    float w[4 + S - 1];                 // sxm[tm .. tm+20), 16B-aligned -> b128s
#pragma unroll
    for (int i = 0; i < 4 + S - 1; i++)
        w[i] = sxm[tm + i];

    float acc[4][4] = {{0.f}};
#pragma unroll
    for (int t = 0; t < S; t++) {
        // one broadcast ds_read_b128 per t (lanes in a 16-group share the address)
        const f32x4 f = *reinterpret_cast<const f32x4*>(&sxf[t][tl]);
#pragma unroll
        for (int j = 0; j < 4; j++) {
            const float b = w[t + j];
            acc[0][j] += f.x * b;
            acc[1][j] += f.y * b;
            acc[2][j] += f.z * b;
            acc[3][j] += f.w * b;
        }
    }

    size_t base = (((size_t)bc * LN) + (size_t)(l0 + tl)) * LN + (size_t)(m0 + tm);
#pragma unroll
    for (int li = 0; li < 4; li++) {
        f32x4 v = { acc[li][0], acc[li][1], acc[li][2], acc[li][3] };
        __builtin_nontemporal_store(v, reinterpret_cast<f32x4*>(out + base + (size_t)li * LN));
    }
}

// ---------------- fallback (round-1 kernel) if ws too small ----------------
__global__ __launch_bounds__(256) void filter_qf_fallback(
    const float* __restrict__ x,
    const float* __restrict__ filt,
    float* __restrict__ out)
{
    const int bc = blockIdx.z;
    const int c  = bc & 1;
    const int l0 = blockIdx.y * TL;
    const int m0 = blockIdx.x * TM;
    const int tid = threadIdx.x;

    __shared__ float sF[S][S];
    __shared__ float sxl[TL + S - 1];
    __shared__ float sxm[TM + S - 1];
    __shared__ float sxf[TL][S + 1];

    const float* __restrict__ xrow = x + (size_t)bc * LN;
    for (int i = tid; i < S * S; i += 256)
        sF[i / S][i % S] = filt[c * S * S + i];
    for (int i = tid; i < TL + S - 1; i += 256) {
        int j = l0 + i - PADW;
        sxl[i] = (j >= 0 && j < LN) ? xrow[j] : 0.0f;
    }
    for (int i = tid; i < TM + S - 1; i += 256) {
        int j = m0 + i - PADW;
        sxm[i] = (j >= 0 && j < LN) ? xrow[j] : 0.0f;
    }
    __syncthreads();
    for (int i = tid; i < TL * S; i += 256) {
        int l = i / S, t = i % S;
        float a = 0.0f;
#pragma unroll
        for (int s = 0; s < S; s++) a += sxl[l + s] * sF[s][t];
        sxf[l][t] = a;
    }
    __syncthreads();
    const int tm = (tid & 15) << 2;
    const int tl = (tid >> 4) << 2;
    float w[4 + S - 1];
#pragma unroll
    for (int i = 0; i < 4 + S - 1; i++) w[i] = sxm[tm + i];
    float acc[4][4] = {{0.f}};
#pragma unroll
    for (int t = 0; t < S; t++) {
        const float f0 = sxf[tl + 0][t], f1 = sxf[tl + 1][t];
        const float f2 = sxf[tl + 2][t], f3 = sxf[tl + 3][t];
#pragma unroll
        for (int j = 0; j < 4; j++) {
            const float b = w[t + j];
            acc[0][j] += f0 * b; acc[1][j] += f1 * b;
            acc[2][j] += f2 * b; acc[3][j] += f3 * b;
        }
    }
    size_t base = (((size_t)bc * LN) + (size_t)(l0 + tl)) * LN + (size_t)(m0 + tm);
#pragma unroll
    for (int li = 0; li < 4; li++) {
        f32x4 v = { acc[li][0], acc[li][1], acc[li][2], acc[li][3] };
        *reinterpret_cast<f32x4*>(out + base + (size_t)li * LN) = v;
    }
}

extern "C" void kernel_launch(void* const* d_in, const int* in_sizes, int n_in,
                              void* d_out, int out_size, void* d_ws, size_t ws_size,
                              hipStream_t stream) {
    const float* x    = (const float*)d_in[0];   // [8,2,2048]
    const float* filt = (const float*)d_in[1];   // [1,2,17,17]
    float* out = (float*)d_out;                  // [8,2,2048,2048]

    const size_t xf_bytes = (size_t)NBC * S * LN * sizeof(float);  // 2.2 MB

    if (ws_size >= xf_bytes) {
        float* xf = (float*)d_ws;
        xf_kernel<<<dim3(LN / 256, NBC), 256, 0, stream>>>(x, filt, xf);
        filter_qf_kernel<<<dim3(LN / TM, LN / TL, NBC), 256, 0, stream>>>(x, xf, out);
    } else {
        filter_qf_fallback<<<dim3(LN / TM, LN / TL, NBC), 256, 0, stream>>>(x, filt, out);
    }
}